// Round 8
// baseline (73.605 us; speedup 1.0000x reference)
//
#include <hip/hip_runtime.h>

#define TWO_LOG2E 2.8853900817779268f

__device__ __forceinline__ float frcp(float x) {
#if __has_builtin(__builtin_amdgcn_rcpf)
  return __builtin_amdgcn_rcpf(x);
#else
  return 1.0f / x;
#endif
}
__device__ __forceinline__ float fexp2(float x) {
#if __has_builtin(__builtin_amdgcn_exp2f)
  return __builtin_amdgcn_exp2f(x);
#else
  return exp2f(x);
#endif
}
__device__ __forceinline__ unsigned short f2bf(float f) {  // RNE f32->bf16
  unsigned int u = __float_as_uint(f);
  u += 0x7fffu + ((u >> 16) & 1u);
  return (unsigned short)(u >> 16);
}
__device__ __forceinline__ unsigned int pack2bf(float lo, float hi) {
  return (unsigned int)f2bf(lo) | ((unsigned int)f2bf(hi) << 16);
}

using short8 = __attribute__((ext_vector_type(8))) short;
using f32x4v = __attribute__((ext_vector_type(4))) float;
using f32x8s = __attribute__((ext_vector_type(8))) float;

// ---------------------------------------------------------------------------
// K1: Aexp = exp(2*query@w1^T) (f32), Bexp = exp(2*key@w2^T) (bf16)
// via bf16 MFMA 16x16x32. M=4096, N=128, K=512. BM=32, BN=64, BK=64.
// grid (128, 2, 2), block 256 (4 waves: wr = m-half(16), wc = n-half(32)).
// ---------------------------------------------------------------------------
__global__ __launch_bounds__(256) void k_proj_mfma(
    const float* __restrict__ query, const float* __restrict__ key,
    const float* __restrict__ w1, const float* __restrict__ w2,
    float* __restrict__ Aout, unsigned short* __restrict__ Bout) {
  const float* in = blockIdx.z ? key : query;
  const float* wm = blockIdx.z ? w2  : w1;

  __shared__ __align__(16) char Abuf[32 * 128];  // [m][k] bf16, swizzled, 4KB
  __shared__ __align__(16) char Bbuf[64 * 128];  // [n][k] bf16, swizzled, 8KB

  const int t = threadIdx.x;
  const int m0g = blockIdx.x * 32;
  const int n0g = blockIdx.y * 64;
  const int w = t >> 6, l = t & 63;
  const int wr = w >> 1, wc = w & 1;

  f32x4v acc[2];
  acc[0] = 0;
  acc[1] = 0;

  const int srow = t >> 3, sg = t & 7;  // staging: row, granule

  for (int k0 = 0; k0 < 512; k0 += 64) {
    if (k0) __syncthreads();
    {  // stage A tile 32m x 64k: 1 granule (8 floats -> 8 bf16) per thread
      const float* src = &in[(m0g + srow) * 512 + k0 + sg * 8];
      float4 f0 = *(const float4*)src;
      float4 f1 = *(const float4*)(src + 4);
      uint4 p = make_uint4(pack2bf(f0.x, f0.y), pack2bf(f0.z, f0.w),
                           pack2bf(f1.x, f1.y), pack2bf(f1.z, f1.w));
      *(uint4*)(Abuf + srow * 128 + ((sg ^ (srow & 7)) << 4)) = p;
    }
#pragma unroll
    for (int i = 0; i < 2; ++i) {  // stage B(w) tile 64n x 64k: 2 granules/thread
      int row = srow + 32 * i;
      const float* src = &wm[(n0g + row) * 512 + k0 + sg * 8];
      float4 f0 = *(const float4*)src;
      float4 f1 = *(const float4*)(src + 4);
      uint4 p = make_uint4(pack2bf(f0.x, f0.y), pack2bf(f0.z, f0.w),
                           pack2bf(f1.x, f1.y), pack2bf(f1.z, f1.w));
      *(uint4*)(Bbuf + row * 128 + ((sg ^ (row & 7)) << 4)) = p;
    }
    __syncthreads();
#pragma unroll
    for (int ks = 0; ks < 2; ++ks) {
      const int gb = ks * 4 + (l >> 4);
      int ra = wr * 16 + (l & 15);
      short8 af = *(const short8*)(Abuf + ra * 128 + ((gb ^ (ra & 7)) << 4));
#pragma unroll
      for (int ni = 0; ni < 2; ++ni) {
        int rb = wc * 32 + ni * 16 + (l & 15);
        short8 bf_ = *(const short8*)(Bbuf + rb * 128 + ((gb ^ (rb & 7)) << 4));
        acc[ni] = __builtin_amdgcn_mfma_f32_16x16x32_bf16(af, bf_, acc[ni], 0, 0, 0);
      }
    }
  }
#pragma unroll
  for (int ni = 0; ni < 2; ++ni) {
    int col = n0g + wc * 32 + ni * 16 + (l & 15);
#pragma unroll
    for (int j = 0; j < 4; ++j) {
      int row = m0g + wr * 16 + (l >> 4) * 4 + j;
      float val = fexp2(acc[ni][j] * TWO_LOG2E);
      if (blockIdx.z == 0)
        Aout[row * 128 + col] = val;
      else
        Bout[row * 128 + col] = f2bf(val);
    }
  }
}

// ---------------------------------------------------------------------------
// k_valT: valT[b][n][k] = bf16(value[b][k][n]).  64x64 tiles, grid (8,8,8).
// ---------------------------------------------------------------------------
__global__ __launch_bounds__(256) void k_valT(
    const float* __restrict__ value, unsigned short* __restrict__ valT) {
  __shared__ unsigned short ts[64][66];
  const int t = threadIdx.x;
  const int b = blockIdx.z, k0 = blockIdx.y * 64, n0 = blockIdx.x * 64;
  {
    int kr = t >> 4, n4 = (t & 15) * 4;
#pragma unroll
    for (int i = 0; i < 4; ++i) {
      float4 f = *(const float4*)&value[((b * 512) + k0 + kr + 16 * i) * 512 + n0 + n4];
      *(ushort4*)&ts[kr + 16 * i][n4] =
          make_ushort4(f2bf(f.x), f2bf(f.y), f2bf(f.z), f2bf(f.w));
    }
  }
  __syncthreads();
  {
    int nw = t >> 4, k4 = (t & 15) * 4;
#pragma unroll
    for (int i = 0; i < 4; ++i) {
      int n = nw + 16 * i;
      ushort4 o = make_ushort4(ts[k4 + 0][n], ts[k4 + 1][n], ts[k4 + 2][n], ts[k4 + 3][n]);
      *(ushort4*)&valT[((b * 512) + n0 + n) * 512 + k0 + k4] = o;
    }
  }
}

// ---------------------------------------------------------------------------
// K2: S[q,k] = sum_h v[h]/(A[q,h]*B[k,h]+1);  attn = softmax_k(-2S).
// 2 q-rows/block, grid (256,8) = 2048 blocks = 8 blocks/CU (8 waves/SIMD).
// LDS B tile: 256 k x 32 h bf16, 17-word row pitch (conflict-free, no swizzle
// VALU). 8 phases (4 h-quarters x 2 k-halves), T14-prefetched. A,v on the
// scalar pipe (s_load_dwordx8). Pair-4 rcp. Waves = 4 k-quarters of the tile.
// ---------------------------------------------------------------------------
__global__ __launch_bounds__(256, 8) void k_score_softmax(
    const float* __restrict__ Aexp, const unsigned short* __restrict__ Bexp,
    const float* __restrict__ vw, float* __restrict__ attn) {
  __shared__ __align__(16) float Bt[256 * 17];  // 17.4KB
  __shared__ float red[4][2];
  char* const BtB = (char*)Bt;

  const int tid = threadIdx.x;
  const int b = blockIdx.y;
  const int qbase = blockIdx.x * 2;
  const int wav = tid >> 6;
  const int lane = tid & 63;

  const int roff0 = (wav * 64 + lane) * 68;  // read base (17 words * 4B)
  const int wbase = tid * 68;                // write base (row = tid)

  // staging source: thread t owns tile-row t; phase kt adds 256 rows (65536B),
  // phase hh selects a 64B quarter of the 256B Bexp row.
  const unsigned char* const bsrc0 =
      (const unsigned char*)Bexp + (b * 512 + tid) * 256;

  // wave-uniform scalar base pointers for the 2 A rows and v
  const float* const pa0 =
      Aexp + __builtin_amdgcn_readfirstlane((b * 512 + qbase) * 128);
  const float* const pa1 = pa0 + 128;
  const float* const pv = vw;

  uint4 stg[4];
#define K2_LOADS(p_)                                                       \
  {                                                                        \
    const uint4* s_ = (const uint4*)(bsrc0 + (((p_) & 1) * 65536) +        \
                                     (((p_) >> 1) * 64));                  \
    stg[0] = s_[0]; stg[1] = s_[1]; stg[2] = s_[2]; stg[3] = s_[3];        \
  }
#define K2_WRITE()                                                         \
  {                                                                        \
    *(unsigned*)(BtB + wbase + 0)  = stg[0].x;                             \
    *(unsigned*)(BtB + wbase + 4)  = stg[0].y;                             \
    *(unsigned*)(BtB + wbase + 8)  = stg[0].z;                             \
    *(unsigned*)(BtB + wbase + 12) = stg[0].w;                             \
    *(unsigned*)(BtB + wbase + 16) = stg[1].x;                             \
    *(unsigned*)(BtB + wbase + 20) = stg[1].y;                             \
    *(unsigned*)(BtB + wbase + 24) = stg[1].z;                             \
    *(unsigned*)(BtB + wbase + 28) = stg[1].w;                             \
    *(unsigned*)(BtB + wbase + 32) = stg[2].x;                             \
    *(unsigned*)(BtB + wbase + 36) = stg[2].y;                             \
    *(unsigned*)(BtB + wbase + 40) = stg[2].z;                             \
    *(unsigned*)(BtB + wbase + 44) = stg[2].w;                             \
    *(unsigned*)(BtB + wbase + 48) = stg[3].x;                             \
    *(unsigned*)(BtB + wbase + 52) = stg[3].y;                             \
    *(unsigned*)(BtB + wbase + 56) = stg[3].z;                             \
    *(unsigned*)(BtB + wbase + 60) = stg[3].w;                             \
  }

// One phase: h-quarter hh = p>>1, k-half kt = p&1; accumulates S for its kt.
#define K2_PHASE(p_, S0_, S1_)                                             \
  {                                                                        \
    const int hh_ = (p_) >> 1;                                             \
    if ((p_) < 7) K2_LOADS((p_) + 1);                                      \
    float s0 = 0.f, s1 = 0.f;                                              \
    _Pragma("unroll") for (int c = 0; c < 4; ++c) {                        \
      f32x8s sa0, sa1, sv;                                                 \
      unsigned soff = (unsigned)(hh_ * 128 + c * 32);                      \
      asm volatile(                                                        \
          "s_load_dwordx8 %0, %3, %6\n\t"                                  \
          "s_load_dwordx8 %1, %4, %6\n\t"                                  \
          "s_load_dwordx8 %2, %5, %6\n\t"                                  \
          "s_waitcnt lgkmcnt(0)"                                           \
          : "=&s"(sa0), "=&s"(sa1), "=&s"(sv)                              \
          : "s"(pa0), "s"(pa1), "s"(pv), "s"(soff));                       \
      _Pragma("unroll") for (int j = 0; j < 2; ++j) {                      \
        const int hgl = c * 2 + j;                                         \
        unsigned lo = *(const unsigned*)(BtB + roff0 + hgl * 8);           \
        unsigned hi = *(const unsigned*)(BtB + roff0 + hgl * 8 + 4);       \
        float b0 = __uint_as_float(lo << 16);                              \
        float b1 = __uint_as_float(lo & 0xffff0000u);                      \
        float b2 = __uint_as_float(hi << 16);                              \
        float b3 = __uint_as_float(hi & 0xffff0000u);                      \
        {                                                                  \
          float x0 = fmaf(sa0[j * 4 + 0], b0, 1.f);                        \
          float x1 = fmaf(sa0[j * 4 + 1], b1, 1.f);                        \
          float x2 = fmaf(sa0[j * 4 + 2], b2, 1.f);                        \
          float x3 = fmaf(sa0[j * 4 + 3], b3, 1.f);                        \
          float p01 = x0 * x1, p23 = x2 * x3;                              \
          float n01 = fmaf(sv[j * 4 + 0], x1, sv[j * 4 + 1] * x0);         \
          float n23 = fmaf(sv[j * 4 + 2], x3, sv[j * 4 + 3] * x2);         \
          float num = fmaf(n01, p23, n23 * p01);                           \
          s0 = fmaf(num, frcp(p01 * p23), s0);                             \
        }                                                                  \
        {                                                                  \
          float x0 = fmaf(sa1[j * 4 + 0], b0, 1.f);                        \
          float x1 = fmaf(sa1[j * 4 + 1], b1, 1.f);                        \
          float x2 = fmaf(sa1[j * 4 + 2], b2, 1.f);                        \
          float x3 = fmaf(sa1[j * 4 + 3], b3, 1.f);                        \
          float p01 = x0 * x1, p23 = x2 * x3;                              \
          float n01 = fmaf(sv[j * 4 + 0], x1, sv[j * 4 + 1] * x0);         \
          float n23 = fmaf(sv[j * 4 + 2], x3, sv[j * 4 + 3] * x2);         \
          float num = fmaf(n01, p23, n23 * p01);                           \
          s1 = fmaf(num, frcp(p01 * p23), s1);                             \
        }                                                                  \
      }                                                                    \
    }                                                                      \
    S0_ += s0;                                                             \
    S1_ += s1;                                                             \
    if ((p_) < 7) { __syncthreads(); K2_WRITE(); __syncthreads(); }        \
  }

  float S00 = 0.f, S01 = 0.f, S10 = 0.f, S11 = 0.f;  // [row][kt]

  K2_LOADS(0);
  K2_WRITE();
  __syncthreads();
  K2_PHASE(0, S00, S10)
  K2_PHASE(1, S01, S11)
  K2_PHASE(2, S00, S10)
  K2_PHASE(3, S01, S11)
  K2_PHASE(4, S00, S10)
  K2_PHASE(5, S01, S11)
  K2_PHASE(6, S00, S10)
  K2_PHASE(7, S01, S11)
#undef K2_LOADS
#undef K2_WRITE
#undef K2_PHASE

  // softmax over k of (-2S): max(score) <-> min(S). Rows span all 4 waves.
  float mn0 = fminf(S00, S01);
  float mn1 = fminf(S10, S11);
#pragma unroll
  for (int off = 32; off > 0; off >>= 1) {
    mn0 = fminf(mn0, __shfl_xor(mn0, off));
    mn1 = fminf(mn1, __shfl_xor(mn1, off));
  }
  if (lane == 0) { red[wav][0] = mn0; red[wav][1] = mn1; }
  __syncthreads();
  mn0 = fminf(fminf(red[0][0], red[1][0]), fminf(red[2][0], red[3][0]));
  mn1 = fminf(fminf(red[0][1], red[1][1]), fminf(red[2][1], red[3][1]));
  __syncthreads();  // before red reuse

  float P00 = fexp2((mn0 - S00) * TWO_LOG2E);
  float P01 = fexp2((mn0 - S01) * TWO_LOG2E);
  float P10 = fexp2((mn1 - S10) * TWO_LOG2E);
  float P11 = fexp2((mn1 - S11) * TWO_LOG2E);
  float sum0 = P00 + P01, sum1 = P10 + P11;
#pragma unroll
  for (int off = 32; off > 0; off >>= 1) {
    sum0 += __shfl_xor(sum0, off);
    sum1 += __shfl_xor(sum1, off);
  }
  if (lane == 0) { red[wav][0] = sum0; red[wav][1] = sum1; }
  __syncthreads();
  float r0 = frcp(red[0][0] + red[1][0] + red[2][0] + red[3][0]);
  float r1 = frcp(red[0][1] + red[1][1] + red[2][1] + red[3][1]);

  const int row0 = (b * 512 + qbase) * 512;
  const int kc = wav * 64 + lane;
  attn[row0 + kc] = P00 * r0;
  attn[row0 + 256 + kc] = P01 * r0;
  attn[row0 + 512 + kc] = P10 * r1;
  attn[row0 + 512 + 256 + kc] = P11 * r1;
}

// ---------------------------------------------------------------------------
// K3: context[b] = attn[b] @ value[b] via bf16 MFMA 16x16x32.
// Tile 64x64, BK=64, 4 waves (2x2), wave tile 32x32 (2x2 frags).
// grid (8,8,8), block 256.
// ---------------------------------------------------------------------------
__global__ __launch_bounds__(256) void k_context_mfma(
    const float* __restrict__ attn, const unsigned short* __restrict__ valT,
    float* __restrict__ ctx) {
  __shared__ __align__(16) char At[64 * 128];  // [m][k] bf16 swizzled, 8KB
  __shared__ __align__(16) char Bt[64 * 128];  // [n][k] bf16 swizzled, 8KB

  const int t = threadIdx.x;
  const int b = blockIdx.z;
  const int m0 = blockIdx.y * 64, n0 = blockIdx.x * 64;
  const int w = t >> 6, l = t & 63;
  const int wr = w >> 1, wc = w & 1;

  f32x4v acc[2][2];
  acc[0][0] = 0; acc[0][1] = 0; acc[1][0] = 0; acc[1][1] = 0;

  const int sr = t >> 2;
  const int sg = (t & 3);
  const int sswz = sr & 7;

  for (int k0 = 0; k0 < 512; k0 += 64) {
    if (k0) __syncthreads();
    {  // stage A: 16 f32 -> 16 bf16 per thread
      const float* src = &attn[(b * 512 + m0 + sr) * 512 + k0 + sg * 16];
      char* dst = At + sr * 128;
#pragma unroll
      for (int h = 0; h < 2; ++h) {
        float4 f0 = *(const float4*)(src + h * 8);
        float4 f1 = *(const float4*)(src + h * 8 + 4);
        uint4 p = make_uint4(pack2bf(f0.x, f0.y), pack2bf(f0.z, f0.w),
                             pack2bf(f1.x, f1.y), pack2bf(f1.z, f1.w));
        int g = sg * 2 + h;
        *(uint4*)(dst + ((g ^ sswz) << 4)) = p;
      }
      // stage B^T: 32 bf16 per thread (already bf16)
      const unsigned short* srcb = &valT[(b * 512 + n0 + sr) * 512 + k0];
      char* dstb = Bt + sr * 128;
#pragma unroll
      for (int h = 0; h < 2; ++h) {
        int g = sg + h * 4;
        uint4 vb = *(const uint4*)(srcb + g * 8);
        *(uint4*)(dstb + ((g ^ sswz) << 4)) = vb;
      }
    }
    __syncthreads();
#pragma unroll
    for (int ks = 0; ks < 2; ++ks) {
      const int gb = ks * 4 + (l >> 4);
      short8 af[2], bf_[2];
#pragma unroll
      for (int mi = 0; mi < 2; ++mi) {
        int ra = wr * 32 + mi * 16 + (l & 15);
        af[mi] = *(const short8*)(At + ra * 128 + ((gb ^ (ra & 7)) << 4));
      }
#pragma unroll
      for (int ni = 0; ni < 2; ++ni) {
        int rb = wc * 32 + ni * 16 + (l & 15);
        bf_[ni] = *(const short8*)(Bt + rb * 128 + ((gb ^ (rb & 7)) << 4));
      }
#pragma unroll
      for (int mi = 0; mi < 2; ++mi)
#pragma unroll
        for (int ni = 0; ni < 2; ++ni)
          acc[mi][ni] = __builtin_amdgcn_mfma_f32_16x16x32_bf16(
              af[mi], bf_[ni], acc[mi][ni], 0, 0, 0);
    }
  }
  __syncthreads();
#pragma unroll
  for (int mi = 0; mi < 2; ++mi)
#pragma unroll
    for (int ni = 0; ni < 2; ++ni) {
      int col = n0 + wc * 32 + ni * 16 + (l & 15);
#pragma unroll
      for (int j = 0; j < 4; ++j) {
        int row = m0 + wr * 32 + mi * 16 + (l >> 4) * 4 + j;
        ctx[(b * 512 + row) * 512 + col] = acc[mi][ni][j];
      }
    }
}

extern "C" void kernel_launch(void* const* d_in, const int* in_sizes, int n_in,
                              void* d_out, int out_size, void* d_ws, size_t ws_size,
                              hipStream_t stream) {
  const float* query = (const float*)d_in[0];
  const float* key   = (const float*)d_in[1];
  const float* value = (const float*)d_in[2];
  const float* w1    = (const float*)d_in[3];
  const float* w2    = (const float*)d_in[4];
  const float* v     = (const float*)d_in[5];

  float* attn = (float*)d_out;
  float* ctx  = attn + 8 * 512 * 512;

  float* Aexp = (float*)d_ws;                                   // 4096*128 f32
  unsigned short* Bexp = (unsigned short*)(Aexp + 4096 * 128);  // 4096*128 bf16
  unsigned short* valT = Bexp + 4096 * 128;                     // 8*512*512 bf16

  k_proj_mfma<<<dim3(128, 2, 2), 256, 0, stream>>>(query, key, w1, w2, Aexp, Bexp);
  k_valT<<<dim3(8, 8, 8), 256, 0, stream>>>(value, valT);
  k_score_softmax<<<dim3(256, 8), 256, 0, stream>>>(Aexp, Bexp, v, attn);
  k_context_mfma<<<dim3(8, 8, 8), 256, 0, stream>>>(attn, valT, ctx);
}